// Round 5
// baseline (196.724 us; speedup 1.0000x reference)
//
#include <hip/hip_runtime.h>
#include <math.h>

typedef __attribute__((ext_vector_type(8))) short bf16x8;
typedef __attribute__((ext_vector_type(4))) float f32x4;

constexpr int D   = 1280;  // input dim
constexpr int H   = 64;    // hidden
constexpr int BM  = 32;    // rows per block (main kernel)
constexpr int KC  = 64;    // K chunk
constexpr int NCH = D / KC;           // 20 chunks
constexpr int CHUNK_SHORTS = 4096;    // 8 frag-rows * 64 lanes * 8 bf16 per chunk
constexpr int WFRAG_ELEMS = (D / 32) * 4 * 64 * 8;  // 81920 bf16 per array
constexpr int HSS = H + 1;

union FragU { bf16x8 v; unsigned int u[4]; };

// truncation split of two f32 into packed bf16 hi pair + bf16 lo pair
__device__ __forceinline__ unsigned int pack_split(float f0, float f1, unsigned int& lo) {
    unsigned int u0 = __float_as_uint(f0), u1 = __float_as_uint(f1);
    unsigned int h0 = u0 & 0xFFFF0000u,    h1 = u1 & 0xFFFF0000u;
    float l0 = f0 - __uint_as_float(h0);
    float l1 = f1 - __uint_as_float(h1);
    lo = (__float_as_uint(l1) & 0xFFFF0000u) | (__float_as_uint(l0) >> 16);
    return h1 | (u0 >> 16);
}

// ---------------- quantum gates: 4-qubit statevector, bit weight BW ----------
template<int BW>
__device__ __forceinline__ void ry_gate(float re[16], float im[16], float theta) {
    float sn, cs;
    sincosf(0.5f * theta, &sn, &cs);
#pragma unroll
    for (int s0 = 0; s0 < 16; ++s0) {
        if (s0 & BW) continue;
        const int s1 = s0 | BW;
        float r0 = re[s0], i0 = im[s0], r1 = re[s1], i1 = im[s1];
        re[s0] = cs * r0 - sn * r1;  im[s0] = cs * i0 - sn * i1;
        re[s1] = sn * r0 + cs * r1;  im[s1] = sn * i0 + cs * i1;
    }
}

template<int BW>
__device__ __forceinline__ void rz_gate(float re[16], float im[16], float theta) {
    float sn, cs;
    sincosf(0.5f * theta, &sn, &cs);
#pragma unroll
    for (int s0 = 0; s0 < 16; ++s0) {
        if (s0 & BW) continue;
        const int s1 = s0 | BW;
        float r0 = re[s0], i0 = im[s0], r1 = re[s1], i1 = im[s1];
        re[s0] = cs * r0 + sn * i0;  im[s0] = cs * i0 - sn * r0;
        re[s1] = cs * r1 - sn * i1;  im[s1] = cs * i1 + sn * r1;
    }
}

template<int BWC, int BWT>
__device__ __forceinline__ void cnot_gate(float re[16], float im[16]) {
#pragma unroll
    for (int s = 0; s < 16; ++s) {
        if (!(s & BWC)) continue;
        if (s & BWT) continue;
        const int t = s | BWT;
        float tr = re[s], ti = im[s];
        re[s] = re[t]; im[s] = im[t];
        re[t] = tr;    im[t] = ti;
    }
}

__device__ __forceinline__ void quantum_row(const float ang[4], const float* __restrict__ qw,
                                            const float* __restrict__ W3, const float* __restrict__ b3,
                                            float* __restrict__ o) {
    float re[16] = {}, im[16] = {};
    re[0] = 1.0f;
    ry_gate<8>(re, im, ang[0]);
    ry_gate<4>(re, im, ang[1]);
    ry_gate<2>(re, im, ang[2]);
    ry_gate<1>(re, im, ang[3]);
#pragma unroll
    for (int ll = 0; ll < 2; ++ll) {
        const float* qp = &qw[ll * 8];
        ry_gate<8>(re, im, qp[0]); rz_gate<8>(re, im, qp[1]);
        ry_gate<4>(re, im, qp[2]); rz_gate<4>(re, im, qp[3]);
        ry_gate<2>(re, im, qp[4]); rz_gate<2>(re, im, qp[5]);
        ry_gate<1>(re, im, qp[6]); rz_gate<1>(re, im, qp[7]);
        cnot_gate<8, 4>(re, im);
        cnot_gate<4, 2>(re, im);
        cnot_gate<2, 1>(re, im);
        cnot_gate<1, 8>(re, im);
    }
    float z[4] = {};
#pragma unroll
    for (int s = 0; s < 16; ++s) {
        float p = re[s] * re[s] + im[s] * im[s];
        z[0] += (s & 8) ? -p : p;
        z[1] += (s & 4) ? -p : p;
        z[2] += (s & 2) ? -p : p;
        z[3] += (s & 1) ? -p : p;
    }
#pragma unroll
    for (int c = 0; c < 10; ++c) {
        float v = b3[c];
#pragma unroll
        for (int i = 0; i < 4; ++i)
            v = fmaf(z[i], W3[c * 4 + i], v);
        o[c] = v;
    }
}

// ================= kernel 1: W1 -> pre-swizzled bf16 hi/lo fragments ==========
// frag index t = (kh*4 + g)*64 + l ; element j=0..7 is W1[g*16+(l&15)][kh*32+(l>>4)*8+j]
__global__ __launch_bounds__(256)
void convert_w1(const float* __restrict__ W1, short* __restrict__ whi, short* __restrict__ wlo) {
    const int t  = blockIdx.x * 256 + threadIdx.x;  // 0..10239
    const int kh = t >> 8;
    const int g  = (t >> 6) & 3;
    const int l  = t & 63;
    const int n  = g * 16 + (l & 15);
    const int k  = kh * 32 + (l >> 4) * 8;
    const float4* p = reinterpret_cast<const float4*>(&W1[(size_t)n * D + k]);
    const float4 a = p[0], b = p[1];
    FragU hi, lo;
    hi.u[0] = pack_split(a.x, a.y, lo.u[0]);
    hi.u[1] = pack_split(a.z, a.w, lo.u[1]);
    hi.u[2] = pack_split(b.x, b.y, lo.u[2]);
    hi.u[3] = pack_split(b.z, b.w, lo.u[3]);
    *reinterpret_cast<bf16x8*>(&whi[(size_t)t * 8]) = hi.v;
    *reinterpret_cast<bf16x8*>(&wlo[(size_t)t * 8]) = lo.v;
}

// ================= kernel 2: BM=32, 128-thread main ===========================
__global__ __launch_bounds__(128, 2)
void fused_qh_v5(const float* __restrict__ x,   const short* __restrict__ whi_g,
                 const short* __restrict__ wlo_g,
                 const float* __restrict__ b1,  const float* __restrict__ bn_g,
                 const float* __restrict__ bn_b,const float* __restrict__ bn_m,
                 const float* __restrict__ bn_v,const float* __restrict__ W2,
                 const float* __restrict__ b2,  const float* __restrict__ qw,
                 const float* __restrict__ W3,  const float* __restrict__ b3,
                 float* __restrict__ out)
{
    __shared__ __align__(16) short wbuf[2 * CHUNK_SHORTS];  // hi | lo, 16 KB
    __shared__ float hs[BM][HSS];
    __shared__ float w2s[4 * H];
    __shared__ float b1s[H], scl[H], shf[H];
    __shared__ float angs[BM][4];

    const int tid  = threadIdx.x;   // 0..127
    const int l    = tid & 63;
    const int w    = tid >> 6;      // wave 0/1 -> row stripe
    const int lr   = l & 15;
    const int lk   = l >> 4;
    const int row0 = blockIdx.x * BM;

    // prologue: small params to LDS
    w2s[tid]       = W2[tid];
    w2s[tid + 128] = W2[tid + 128];
    if (tid < H) {
        float s = bn_g[tid] * rsqrtf(bn_v[tid] + 1e-5f);
        b1s[tid] = b1[tid];
        scl[tid] = s;
        shf[tid] = bn_b[tid] - bn_m[tid] * s;
    }

    const float4* xr4 = reinterpret_cast<const float4*>(x + (size_t)(row0 + w * 16 + lr) * D);
    const uint4*  WHg = reinterpret_cast<const uint4*>(whi_g);  // 512 uint4 per chunk
    const uint4*  WLg = reinterpret_cast<const uint4*>(wlo_g);

    f32x4 acc[4] = {{0,0,0,0},{0,0,0,0},{0,0,0,0},{0,0,0,0}};

    // thread stages 4 uint4 of hi + 4 of lo per chunk; slot = q*128 + tid (lane-contiguous)
#define LOADW(dh, dl, c)                                   \
    {                                                      \
        _Pragma("unroll")                                  \
        for (int q = 0; q < 4; ++q) {                      \
            dh[q] = WHg[(c) * 512 + q * 128 + tid];        \
            dl[q] = WLg[(c) * 512 + q * 128 + tid];        \
        }                                                  \
    }

#define LOADX(dst, c)                                                  \
    {                                                                  \
        _Pragma("unroll")                                              \
        for (int i = 0; i < 4; ++i)                                    \
            dst[i] = xr4[(c) * 16 + (i >> 1) * 8 + lk * 2 + (i & 1)];  \
    }

    uint4  wh[4], wl[4], nwh[4], nwl[4];
    float4 a0[4], a1[4], a2[4];

    LOADW(wh, wl, 0);
    LOADX(a0, 0);
    LOADX(a1, 1);

#pragma unroll 4
    for (int c = 0; c < NCH; ++c) {
        // stage current W chunk (pure copy, conflict-free: byte addr = slot*16)
#pragma unroll
        for (int q = 0; q < 4; ++q) {
            *reinterpret_cast<uint4*>(&wbuf[(q * 128 + tid) * 8])                = wh[q];
            *reinterpret_cast<uint4*>(&wbuf[CHUNK_SHORTS + (q * 128 + tid) * 8]) = wl[q];
        }
        // prefetch next W chunk + x two chunks ahead
        if (c + 1 < NCH) LOADW(nwh, nwl, c + 1);
        if (c + 2 < NCH) LOADX(a2, c + 2);
        __syncthreads();

        // A frags (hi/lo split of x)
        FragU ahi[2], alo[2];
#pragma unroll
        for (int h = 0; h < 2; ++h) {
            const float4 p0 = a0[h * 2 + 0];
            const float4 p1 = a0[h * 2 + 1];
            ahi[h].u[0] = pack_split(p0.x, p0.y, alo[h].u[0]);
            ahi[h].u[1] = pack_split(p0.z, p0.w, alo[h].u[1]);
            ahi[h].u[2] = pack_split(p1.x, p1.y, alo[h].u[2]);
            ahi[h].u[3] = pack_split(p1.z, p1.w, alo[h].u[3]);
        }

#pragma unroll
        for (int h = 0; h < 2; ++h)
#pragma unroll
            for (int g = 0; g < 4; ++g) {
                const int f = h * 4 + g;
                const bf16x8 bh = *reinterpret_cast<const bf16x8*>(&wbuf[f * 512 + l * 8]);
                const bf16x8 bl = *reinterpret_cast<const bf16x8*>(&wbuf[CHUNK_SHORTS + f * 512 + l * 8]);
                acc[g] = __builtin_amdgcn_mfma_f32_16x16x32_bf16(ahi[h].v, bh, acc[g], 0, 0, 0);
                acc[g] = __builtin_amdgcn_mfma_f32_16x16x32_bf16(ahi[h].v, bl, acc[g], 0, 0, 0);
                acc[g] = __builtin_amdgcn_mfma_f32_16x16x32_bf16(alo[h].v, bh, acc[g], 0, 0, 0);
            }

        __syncthreads();

#pragma unroll
        for (int q = 0; q < 4; ++q) { wh[q] = nwh[q]; wl[q] = nwl[q]; }
#pragma unroll
        for (int i = 0; i < 4; ++i) { a0[i] = a1[i]; a1[i] = a2[i]; }
    }
#undef LOADW
#undef LOADX

    // epilogue 1: bias -> relu -> BN -> hs (C/D: col=g*16+lr, row=lk*4+reg)
#pragma unroll
    for (int g = 0; g < 4; ++g) {
        const int cc = g * 16 + lr;
        const float b1c = b1s[cc], s = scl[cc], sh = shf[cc];
#pragma unroll
        for (int r = 0; r < 4; ++r) {
            float v = acc[g][r] + b1c;
            v = fmaxf(v, 0.0f) * s + sh;
            hs[w * 16 + lk * 4 + r][cc] = v;
        }
    }
    __syncthreads();

    // epilogue 2a: GEMM2 + double tanh, 4 threads per row (128 = 32 rows * 4)
    {
        const int row = tid >> 2, qi = tid & 3;
        float a2v = b2[qi];
#pragma unroll
        for (int k = 0; k < H; ++k)
            a2v = fmaf(hs[row][k], w2s[qi * H + k], a2v);
        float xq = tanhf(a2v);
        angs[row][qi] = tanhf(xq) * 3.14159265358979323846f;
    }
    __syncthreads();

    // epilogue 2b: quantum circuit + GEMM3, one thread per row
    if (tid < BM) {
        float ang[4] = { angs[tid][0], angs[tid][1], angs[tid][2], angs[tid][3] };
        quantum_row(ang, qw, W3, b3, &out[(size_t)(row0 + tid) * 10]);
    }
}

// ================= fallback (verified round-2 kernel, used if ws too small) ===
constexpr int SW  = KC + 8;
constexpr int BMF = 64;

__global__ __launch_bounds__(256, 2)
void fused_qh_mfma(const float* __restrict__ x,   const float* __restrict__ W1,
                   const float* __restrict__ b1,  const float* __restrict__ bn_g,
                   const float* __restrict__ bn_b,const float* __restrict__ bn_m,
                   const float* __restrict__ bn_v,const float* __restrict__ W2,
                   const float* __restrict__ b2,  const float* __restrict__ qw,
                   const float* __restrict__ W3,  const float* __restrict__ b3,
                   float* __restrict__ out)
{
    __shared__ short whi[H][SW];
    __shared__ short wlo[H][SW];
    __shared__ float hs[BMF][HSS];
    __shared__ float w2s[4 * H];
    __shared__ float b1s[H], scl[H], shf[H];

    const int tid  = threadIdx.x;
    const int l    = tid & 63;
    const int w    = tid >> 6;
    const int lr   = l & 15;
    const int lk   = l >> 4;
    const int row0 = blockIdx.x * BMF;

    w2s[tid] = W2[tid];
    if (tid < H) {
        float s = bn_g[tid] * rsqrtf(bn_v[tid] + 1e-5f);
        b1s[tid] = b1[tid];
        scl[tid] = s;
        shf[tid] = bn_b[tid] - bn_m[tid] * s;
    }

    const float4* xr4 = reinterpret_cast<const float4*>(x + (size_t)(row0 + w * 16 + lr) * D);

    int sn[4], sk4[4];
#pragma unroll
    for (int it = 0; it < 4; ++it) {
        int f4 = tid + it * 256;
        sn[it]  = f4 >> 4;
        sk4[it] = (f4 & 15) * 4;
    }

    f32x4 acc[4] = {{0,0,0,0},{0,0,0,0},{0,0,0,0},{0,0,0,0}};
    float4 acur[4], anxt[4], wcur[4], wnxt[4];
#pragma unroll
    for (int it = 0; it < 4; ++it)
        wcur[it] = *reinterpret_cast<const float4*>(&W1[(size_t)sn[it] * D + sk4[it]]);
#pragma unroll
    for (int h = 0; h < 2; ++h)
#pragma unroll
        for (int p = 0; p < 2; ++p)
            acur[h * 2 + p] = xr4[h * 8 + lk * 2 + p];

    for (int k0 = 0; k0 < D; k0 += KC) {
#pragma unroll
        for (int it = 0; it < 4; ++it) {
            unsigned int lo01, lo23;
            unsigned int hi01 = pack_split(wcur[it].x, wcur[it].y, lo01);
            unsigned int hi23 = pack_split(wcur[it].z, wcur[it].w, lo23);
            uint2 hv; hv.x = hi01; hv.y = hi23;
            uint2 lv; lv.x = lo01; lv.y = lo23;
            *reinterpret_cast<uint2*>(&whi[sn[it]][sk4[it]]) = hv;
            *reinterpret_cast<uint2*>(&wlo[sn[it]][sk4[it]]) = lv;
        }
        if (k0 + KC < D) {
            const int kn = k0 + KC;
#pragma unroll
            for (int it = 0; it < 4; ++it)
                wnxt[it] = *reinterpret_cast<const float4*>(&W1[(size_t)sn[it] * D + kn + sk4[it]]);
#pragma unroll
            for (int h = 0; h < 2; ++h)
#pragma unroll
                for (int p = 0; p < 2; ++p)
                    anxt[h * 2 + p] = xr4[kn / 4 + h * 8 + lk * 2 + p];
        }
        __syncthreads();

        FragU ahi[2], alo[2];
#pragma unroll
        for (int h = 0; h < 2; ++h) {
            const float4 p0 = acur[h * 2 + 0];
            const float4 p1 = acur[h * 2 + 1];
            ahi[h].u[0] = pack_split(p0.x, p0.y, alo[h].u[0]);
            ahi[h].u[1] = pack_split(p0.z, p0.w, alo[h].u[1]);
            ahi[h].u[2] = pack_split(p1.x, p1.y, alo[h].u[2]);
            ahi[h].u[3] = pack_split(p1.z, p1.w, alo[h].u[3]);
        }
#pragma unroll
        for (int h = 0; h < 2; ++h)
#pragma unroll
            for (int g = 0; g < 4; ++g) {
                const bf16x8 bh = *reinterpret_cast<const bf16x8*>(&whi[g * 16 + lr][h * 32 + lk * 8]);
                const bf16x8 bl = *reinterpret_cast<const bf16x8*>(&wlo[g * 16 + lr][h * 32 + lk * 8]);
                acc[g] = __builtin_amdgcn_mfma_f32_16x16x32_bf16(ahi[h].v, bh, acc[g], 0, 0, 0);
                acc[g] = __builtin_amdgcn_mfma_f32_16x16x32_bf16(ahi[h].v, bl, acc[g], 0, 0, 0);
                acc[g] = __builtin_amdgcn_mfma_f32_16x16x32_bf16(alo[h].v, bh, acc[g], 0, 0, 0);
            }
        __syncthreads();

#pragma unroll
        for (int it = 0; it < 4; ++it) { acur[it] = anxt[it]; wcur[it] = wnxt[it]; }
    }

#pragma unroll
    for (int g = 0; g < 4; ++g) {
        const int c = g * 16 + lr;
        const float b1c = b1s[c], s = scl[c], sh = shf[c];
#pragma unroll
        for (int r = 0; r < 4; ++r) {
            float v = acc[g][r] + b1c;
            v = fmaxf(v, 0.0f) * s + sh;
            hs[w * 16 + lk * 4 + r][c] = v;
        }
    }
    __syncthreads();

    if (tid < BMF) {
        const int row = tid;
        float ang[4];
#pragma unroll
        for (int qi = 0; qi < 4; ++qi) {
            float a2 = b2[qi];
            for (int k = 0; k < H; ++k)
                a2 = fmaf(hs[row][k], w2s[qi * H + k], a2);
            float xq = tanhf(a2);
            ang[qi] = tanhf(xq) * 3.14159265358979323846f;
        }
        quantum_row(ang, qw, W3, b3, &out[(size_t)(row0 + row) * 10]);
    }
}

extern "C" void kernel_launch(void* const* d_in, const int* in_sizes, int n_in,
                              void* d_out, int out_size, void* d_ws, size_t ws_size,
                              hipStream_t stream) {
    const float* x    = (const float*)d_in[0];
    const float* W1   = (const float*)d_in[1];
    const float* b1   = (const float*)d_in[2];
    const float* bn_g = (const float*)d_in[3];
    const float* bn_b = (const float*)d_in[4];
    const float* bn_m = (const float*)d_in[5];
    const float* bn_v = (const float*)d_in[6];
    const float* W2   = (const float*)d_in[7];
    const float* b2   = (const float*)d_in[8];
    const float* qw   = (const float*)d_in[9];
    const float* W3   = (const float*)d_in[10];
    const float* b3   = (const float*)d_in[11];
    float* out = (float*)d_out;

    const int B = in_sizes[0] / D;   // 32768

    const size_t need = (size_t)2 * WFRAG_ELEMS * sizeof(short);  // 327,680 B
    if (ws_size >= need) {
        short* whi_ws = (short*)d_ws;
        short* wlo_ws = whi_ws + WFRAG_ELEMS;
        convert_w1<<<(WFRAG_ELEMS / 8) / 256, 256, 0, stream>>>(W1, whi_ws, wlo_ws);
        fused_qh_v5<<<B / BM, 128, 0, stream>>>(
            x, whi_ws, wlo_ws, b1, bn_g, bn_b, bn_m, bn_v, W2, b2, qw, W3, b3, out);
    } else {
        fused_qh_mfma<<<B / BMF, 256, 0, stream>>>(
            x, W1, b1, bn_g, bn_b, bn_m, bn_v, W2, b2, qw, W3, b3, out);
    }
}

// Round 7
// 125.100 us; speedup vs baseline: 1.5725x; 1.5725x over previous
//
#include <hip/hip_runtime.h>
#include <math.h>

typedef __attribute__((ext_vector_type(8))) short bf16x8;
typedef __attribute__((ext_vector_type(4))) float f32x4;

constexpr int D   = 1280;  // input dim
constexpr int H   = 64;    // hidden
constexpr int BM  = 64;    // rows per block
constexpr int KC  = 64;    // K chunk
constexpr int NCH = D / KC;           // 20 chunks
constexpr int CHUNK_SHORTS = 4096;    // hi half of one chunk: 8 frag-rows * 64 lanes * 8 bf16
constexpr int WFRAG_ELEMS = (D / 32) * 4 * 64 * 8;  // 81920 bf16 per array
constexpr int HSS = H + 1;

union FragU { bf16x8 v; unsigned int u[4]; };

// truncation split of two f32 into packed bf16 hi pair + bf16 lo pair
__device__ __forceinline__ unsigned int pack_split(float f0, float f1, unsigned int& lo) {
    unsigned int u0 = __float_as_uint(f0), u1 = __float_as_uint(f1);
    unsigned int h0 = u0 & 0xFFFF0000u,    h1 = u1 & 0xFFFF0000u;
    float l0 = f0 - __uint_as_float(h0);
    float l1 = f1 - __uint_as_float(h1);
    lo = (__float_as_uint(l1) & 0xFFFF0000u) | (__float_as_uint(l0) >> 16);
    return h1 | (u0 >> 16);
}

// ---------------- quantum gates: 4-qubit statevector, bit weight BW ----------
template<int BW>
__device__ __forceinline__ void ry_gate(float re[16], float im[16], float theta) {
    float sn, cs;
    sincosf(0.5f * theta, &sn, &cs);
#pragma unroll
    for (int s0 = 0; s0 < 16; ++s0) {
        if (s0 & BW) continue;
        const int s1 = s0 | BW;
        float r0 = re[s0], i0 = im[s0], r1 = re[s1], i1 = im[s1];
        re[s0] = cs * r0 - sn * r1;  im[s0] = cs * i0 - sn * i1;
        re[s1] = sn * r0 + cs * r1;  im[s1] = sn * i0 + cs * i1;
    }
}

template<int BW>
__device__ __forceinline__ void rz_gate(float re[16], float im[16], float theta) {
    float sn, cs;
    sincosf(0.5f * theta, &sn, &cs);
#pragma unroll
    for (int s0 = 0; s0 < 16; ++s0) {
        if (s0 & BW) continue;
        const int s1 = s0 | BW;
        float r0 = re[s0], i0 = im[s0], r1 = re[s1], i1 = im[s1];
        re[s0] = cs * r0 + sn * i0;  im[s0] = cs * i0 - sn * r0;
        re[s1] = cs * r1 - sn * i1;  im[s1] = cs * i1 + sn * r1;
    }
}

template<int BWC, int BWT>
__device__ __forceinline__ void cnot_gate(float re[16], float im[16]) {
#pragma unroll
    for (int s = 0; s < 16; ++s) {
        if (!(s & BWC)) continue;
        if (s & BWT) continue;
        const int t = s | BWT;
        float tr = re[s], ti = im[s];
        re[s] = re[t]; im[s] = im[t];
        re[t] = tr;    im[t] = ti;
    }
}

__device__ __forceinline__ void quantum_row(const float ang[4], const float* __restrict__ qw,
                                            const float* __restrict__ W3, const float* __restrict__ b3,
                                            float* __restrict__ o) {
    float re[16] = {}, im[16] = {};
    re[0] = 1.0f;
    ry_gate<8>(re, im, ang[0]);
    ry_gate<4>(re, im, ang[1]);
    ry_gate<2>(re, im, ang[2]);
    ry_gate<1>(re, im, ang[3]);
#pragma unroll
    for (int ll = 0; ll < 2; ++ll) {
        const float* qp = &qw[ll * 8];
        ry_gate<8>(re, im, qp[0]); rz_gate<8>(re, im, qp[1]);
        ry_gate<4>(re, im, qp[2]); rz_gate<4>(re, im, qp[3]);
        ry_gate<2>(re, im, qp[4]); rz_gate<2>(re, im, qp[5]);
        ry_gate<1>(re, im, qp[6]); rz_gate<1>(re, im, qp[7]);
        cnot_gate<8, 4>(re, im);
        cnot_gate<4, 2>(re, im);
        cnot_gate<2, 1>(re, im);
        cnot_gate<1, 8>(re, im);
    }
    float z[4] = {};
#pragma unroll
    for (int s = 0; s < 16; ++s) {
        float p = re[s] * re[s] + im[s] * im[s];
        z[0] += (s & 8) ? -p : p;
        z[1] += (s & 4) ? -p : p;
        z[2] += (s & 2) ? -p : p;
        z[3] += (s & 1) ? -p : p;
    }
#pragma unroll
    for (int c = 0; c < 10; ++c) {
        float v = b3[c];
#pragma unroll
        for (int i = 0; i < 4; ++i)
            v = fmaf(z[i], W3[c * 4 + i], v);
        o[c] = v;
    }
}

// ================= kernel 1: W1 -> pre-swizzled bf16 hi/lo fragments ==========
// frag index t = (kh*4 + g)*64 + l ; element j=0..7 is W1[g*16+(l&15)][kh*32+(l>>4)*8+j]
__global__ __launch_bounds__(256)
void convert_w1(const float* __restrict__ W1, short* __restrict__ whi, short* __restrict__ wlo) {
    const int t  = blockIdx.x * 256 + threadIdx.x;  // 0..10239
    const int kh = t >> 8;
    const int g  = (t >> 6) & 3;
    const int l  = t & 63;
    const int n  = g * 16 + (l & 15);
    const int k  = kh * 32 + (l >> 4) * 8;
    const float4* p = reinterpret_cast<const float4*>(&W1[(size_t)n * D + k]);
    const float4 a = p[0], b = p[1];
    FragU hi, lo;
    hi.u[0] = pack_split(a.x, a.y, lo.u[0]);
    hi.u[1] = pack_split(a.z, a.w, lo.u[1]);
    hi.u[2] = pack_split(b.x, b.y, lo.u[2]);
    hi.u[3] = pack_split(b.z, b.w, lo.u[3]);
    *reinterpret_cast<bf16x8*>(&whi[(size_t)t * 8]) = hi.v;
    *reinterpret_cast<bf16x8*>(&wlo[(size_t)t * 8]) = lo.v;
}

// ================= kernel 2: r2 structure + pre-split W (2 barriers/chunk) ====
__global__ __launch_bounds__(256, 2)
void fused_qh_v7(const float* __restrict__ x,   const short* __restrict__ whi_g,
                 const short* __restrict__ wlo_g,
                 const float* __restrict__ b1,  const float* __restrict__ bn_g,
                 const float* __restrict__ bn_b,const float* __restrict__ bn_m,
                 const float* __restrict__ bn_v,const float* __restrict__ W2,
                 const float* __restrict__ b2,  const float* __restrict__ qw,
                 const float* __restrict__ W3,  const float* __restrict__ b3,
                 float* __restrict__ out)
{
    __shared__ __align__(16) short wbuf[2 * CHUNK_SHORTS];  // hi [0,4096) | lo [4096,8192), 16 KB
    __shared__ float hs[BM][HSS];
    __shared__ float w2s[4 * H];
    __shared__ float b1s[H], scl[H], shf[H];
    __shared__ float angs[BM][4];

    const int tid  = threadIdx.x;   // 0..255
    const int l    = tid & 63;
    const int w    = tid >> 6;      // wave 0..3 -> row stripe
    const int lr   = l & 15;
    const int lk   = l >> 4;
    const int row0 = blockIdx.x * BM;

    // prologue: small params to LDS
    w2s[tid] = W2[tid];
    if (tid < H) {
        float s = bn_g[tid] * rsqrtf(bn_v[tid] + 1e-5f);
        b1s[tid] = b1[tid];
        scl[tid] = s;
        shf[tid] = bn_b[tid] - bn_m[tid] * s;
    }

    const float4* xr4 = reinterpret_cast<const float4*>(x + (size_t)(row0 + w * 16 + lr) * D);
    const uint4*  WHg = reinterpret_cast<const uint4*>(whi_g);  // 512 uint4 per chunk
    const uint4*  WLg = reinterpret_cast<const uint4*>(wlo_g);

    f32x4 acc[4] = {{0,0,0,0},{0,0,0,0},{0,0,0,0},{0,0,0,0}};

    // per-thread W staging: 2 uint4 of hi + 2 of lo per chunk, slot-contiguous
#define LOADW(dst, c)                                      \
    {                                                      \
        _Pragma("unroll")                                  \
        for (int q = 0; q < 2; ++q) {                      \
            dst[q]     = WHg[(c) * 512 + q * 256 + tid];   \
            dst[2 + q] = WLg[(c) * 512 + q * 256 + tid];   \
        }                                                  \
    }

#define STOREW(src)                                                                        \
    {                                                                                      \
        _Pragma("unroll")                                                                  \
        for (int q = 0; q < 2; ++q) {                                                      \
            *reinterpret_cast<uint4*>(&wbuf[(q * 256 + tid) * 8])                = src[q];     \
            *reinterpret_cast<uint4*>(&wbuf[CHUNK_SHORTS + (q * 256 + tid) * 8]) = src[2 + q]; \
        }                                                                                  \
    }

#define LOADX(dst, c)                                                  \
    {                                                                  \
        _Pragma("unroll")                                              \
        for (int i = 0; i < 4; ++i)                                    \
            dst[i] = xr4[(c) * 16 + (i >> 1) * 8 + lk * 2 + (i & 1)];  \
    }

    uint4  wcur[4], wnxt[4];
    float4 acur[4], anxt[4];

    LOADW(wcur, 0);
    LOADX(acur, 0);

    for (int c = 0; c < NCH; ++c) {
        // stage current W chunk into LDS (pure uint4 copy)
        STOREW(wcur);
        // prefetch next chunk into registers
        if (c + 1 < NCH) {
            LOADW(wnxt, c + 1);
            LOADX(anxt, c + 1);
        }
        __syncthreads();

        // A frags (hi/lo split of x)
        FragU ahi[2], alo[2];
#pragma unroll
        for (int h = 0; h < 2; ++h) {
            const float4 p0 = acur[h * 2 + 0];
            const float4 p1 = acur[h * 2 + 1];
            ahi[h].u[0] = pack_split(p0.x, p0.y, alo[h].u[0]);
            ahi[h].u[1] = pack_split(p0.z, p0.w, alo[h].u[1]);
            ahi[h].u[2] = pack_split(p1.x, p1.y, alo[h].u[2]);
            ahi[h].u[3] = pack_split(p1.z, p1.w, alo[h].u[3]);
        }

#pragma unroll
        for (int h = 0; h < 2; ++h)
#pragma unroll
            for (int g = 0; g < 4; ++g) {
                const int f = h * 4 + g;
                const bf16x8 bh = *reinterpret_cast<const bf16x8*>(&wbuf[f * 512 + l * 8]);
                const bf16x8 bl = *reinterpret_cast<const bf16x8*>(&wbuf[CHUNK_SHORTS + f * 512 + l * 8]);
                acc[g] = __builtin_amdgcn_mfma_f32_16x16x32_bf16(ahi[h].v, bh, acc[g], 0, 0, 0);
                acc[g] = __builtin_amdgcn_mfma_f32_16x16x32_bf16(ahi[h].v, bl, acc[g], 0, 0, 0);
                acc[g] = __builtin_amdgcn_mfma_f32_16x16x32_bf16(alo[h].v, bh, acc[g], 0, 0, 0);
            }

        __syncthreads();

#pragma unroll
        for (int q = 0; q < 4; ++q) wcur[q] = wnxt[q];
#pragma unroll
        for (int i = 0; i < 4; ++i) acur[i] = anxt[i];
    }
#undef LOADW
#undef STOREW
#undef LOADX

    // epilogue 1: bias -> relu -> BN -> hs (C/D: col=g*16+lr, row=lk*4+reg)
#pragma unroll
    for (int g = 0; g < 4; ++g) {
        const int cc = g * 16 + lr;
        const float b1c = b1s[cc], s = scl[cc], sh = shf[cc];
#pragma unroll
        for (int r = 0; r < 4; ++r) {
            float v = acc[g][r] + b1c;
            v = fmaxf(v, 0.0f) * s + sh;
            hs[w * 16 + lk * 4 + r][cc] = v;
        }
    }
    __syncthreads();

    // epilogue 2a: GEMM2 + double tanh, 4 threads per row (256 = 64 rows * 4)
    {
        const int row = tid >> 2, qi = tid & 3;
        float a2v = b2[qi];
#pragma unroll
        for (int k = 0; k < H; ++k)
            a2v = fmaf(hs[row][k], w2s[qi * H + k], a2v);
        float xq = tanhf(a2v);
        angs[row][qi] = tanhf(xq) * 3.14159265358979323846f;
    }
    __syncthreads();

    // epilogue 2b: quantum circuit + GEMM3, one thread per row
    if (tid < BM) {
        float ang[4] = { angs[tid][0], angs[tid][1], angs[tid][2], angs[tid][3] };
        quantum_row(ang, qw, W3, b3, &out[(size_t)(row0 + tid) * 10]);
    }
}

// ================= fallback (verified round-2 kernel, used if ws too small) ===
constexpr int SW  = KC + 8;

__global__ __launch_bounds__(256, 2)
void fused_qh_mfma(const float* __restrict__ x,   const float* __restrict__ W1,
                   const float* __restrict__ b1,  const float* __restrict__ bn_g,
                   const float* __restrict__ bn_b,const float* __restrict__ bn_m,
                   const float* __restrict__ bn_v,const float* __restrict__ W2,
                   const float* __restrict__ b2,  const float* __restrict__ qw,
                   const float* __restrict__ W3,  const float* __restrict__ b3,
                   float* __restrict__ out)
{
    __shared__ short whi[H][SW];
    __shared__ short wlo[H][SW];
    __shared__ float hs[BM][HSS];
    __shared__ float w2s[4 * H];
    __shared__ float b1s[H], scl[H], shf[H];

    const int tid  = threadIdx.x;
    const int l    = tid & 63;
    const int w    = tid >> 6;
    const int lr   = l & 15;
    const int lk   = l >> 4;
    const int row0 = blockIdx.x * BM;

    w2s[tid] = W2[tid];
    if (tid < H) {
        float s = bn_g[tid] * rsqrtf(bn_v[tid] + 1e-5f);
        b1s[tid] = b1[tid];
        scl[tid] = s;
        shf[tid] = bn_b[tid] - bn_m[tid] * s;
    }

    const float4* xr4 = reinterpret_cast<const float4*>(x + (size_t)(row0 + w * 16 + lr) * D);

    int sn[4], sk4[4];
#pragma unroll
    for (int it = 0; it < 4; ++it) {
        int f4 = tid + it * 256;
        sn[it]  = f4 >> 4;
        sk4[it] = (f4 & 15) * 4;
    }

    f32x4 acc[4] = {{0,0,0,0},{0,0,0,0},{0,0,0,0},{0,0,0,0}};
    float4 acur[4], anxt[4], wcur[4], wnxt[4];
#pragma unroll
    for (int it = 0; it < 4; ++it)
        wcur[it] = *reinterpret_cast<const float4*>(&W1[(size_t)sn[it] * D + sk4[it]]);
#pragma unroll
    for (int h = 0; h < 2; ++h)
#pragma unroll
        for (int p = 0; p < 2; ++p)
            acur[h * 2 + p] = xr4[h * 8 + lk * 2 + p];

    for (int k0 = 0; k0 < D; k0 += KC) {
#pragma unroll
        for (int it = 0; it < 4; ++it) {
            unsigned int lo01, lo23;
            unsigned int hi01 = pack_split(wcur[it].x, wcur[it].y, lo01);
            unsigned int hi23 = pack_split(wcur[it].z, wcur[it].w, lo23);
            uint2 hv; hv.x = hi01; hv.y = hi23;
            uint2 lv; lv.x = lo01; lv.y = lo23;
            *reinterpret_cast<uint2*>(&whi[sn[it]][sk4[it]]) = hv;
            *reinterpret_cast<uint2*>(&wlo[sn[it]][sk4[it]]) = lv;
        }
        if (k0 + KC < D) {
            const int kn = k0 + KC;
#pragma unroll
            for (int it = 0; it < 4; ++it)
                wnxt[it] = *reinterpret_cast<const float4*>(&W1[(size_t)sn[it] * D + kn + sk4[it]]);
#pragma unroll
            for (int h = 0; h < 2; ++h)
#pragma unroll
                for (int p = 0; p < 2; ++p)
                    anxt[h * 2 + p] = xr4[kn / 4 + h * 8 + lk * 2 + p];
        }
        __syncthreads();

        FragU ahi[2], alo[2];
#pragma unroll
        for (int h = 0; h < 2; ++h) {
            const float4 p0 = acur[h * 2 + 0];
            const float4 p1 = acur[h * 2 + 1];
            ahi[h].u[0] = pack_split(p0.x, p0.y, alo[h].u[0]);
            ahi[h].u[1] = pack_split(p0.z, p0.w, alo[h].u[1]);
            ahi[h].u[2] = pack_split(p1.x, p1.y, alo[h].u[2]);
            ahi[h].u[3] = pack_split(p1.z, p1.w, alo[h].u[3]);
        }
#pragma unroll
        for (int h = 0; h < 2; ++h)
#pragma unroll
            for (int g = 0; g < 4; ++g) {
                const bf16x8 bh = *reinterpret_cast<const bf16x8*>(&whi[g * 16 + lr][h * 32 + lk * 8]);
                const bf16x8 bl = *reinterpret_cast<const bf16x8*>(&wlo[g * 16 + lr][h * 32 + lk * 8]);
                acc[g] = __builtin_amdgcn_mfma_f32_16x16x32_bf16(ahi[h].v, bh, acc[g], 0, 0, 0);
                acc[g] = __builtin_amdgcn_mfma_f32_16x16x32_bf16(ahi[h].v, bl, acc[g], 0, 0, 0);
                acc[g] = __builtin_amdgcn_mfma_f32_16x16x32_bf16(alo[h].v, bh, acc[g], 0, 0, 0);
            }
        __syncthreads();

#pragma unroll
        for (int it = 0; it < 4; ++it) { acur[it] = anxt[it]; wcur[it] = wnxt[it]; }
    }

#pragma unroll
    for (int g = 0; g < 4; ++g) {
        const int c = g * 16 + lr;
        const float b1c = b1s[c], s = scl[c], sh = shf[c];
#pragma unroll
        for (int r = 0; r < 4; ++r) {
            float v = acc[g][r] + b1c;
            v = fmaxf(v, 0.0f) * s + sh;
            hs[w * 16 + lk * 4 + r][c] = v;
        }
    }
    __syncthreads();

    if (tid < BM) {
        const int row = tid;
        float ang[4];
#pragma unroll
        for (int qi = 0; qi < 4; ++qi) {
            float a2 = b2[qi];
            for (int k = 0; k < H; ++k)
                a2 = fmaf(hs[row][k], w2s[qi * H + k], a2);
            float xq = tanhf(a2);
            ang[qi] = tanhf(xq) * 3.14159265358979323846f;
        }
        quantum_row(ang, qw, W3, b3, &out[(size_t)(row0 + row) * 10]);
    }
}

extern "C" void kernel_launch(void* const* d_in, const int* in_sizes, int n_in,
                              void* d_out, int out_size, void* d_ws, size_t ws_size,
                              hipStream_t stream) {
    const float* x    = (const float*)d_in[0];
    const float* W1   = (const float*)d_in[1];
    const float* b1   = (const float*)d_in[2];
    const float* bn_g = (const float*)d_in[3];
    const float* bn_b = (const float*)d_in[4];
    const float* bn_m = (const float*)d_in[5];
    const float* bn_v = (const float*)d_in[6];
    const float* W2   = (const float*)d_in[7];
    const float* b2   = (const float*)d_in[8];
    const float* qw   = (const float*)d_in[9];
    const float* W3   = (const float*)d_in[10];
    const float* b3   = (const float*)d_in[11];
    float* out = (float*)d_out;

    const int B = in_sizes[0] / D;   // 32768

    const size_t need = (size_t)2 * WFRAG_ELEMS * sizeof(short);  // 327,680 B
    if (ws_size >= need) {
        short* whi_ws = (short*)d_ws;
        short* wlo_ws = whi_ws + WFRAG_ELEMS;
        convert_w1<<<(WFRAG_ELEMS / 8) / 256, 256, 0, stream>>>(W1, whi_ws, wlo_ws);
        fused_qh_v7<<<B / BM, 256, 0, stream>>>(
            x, whi_ws, wlo_ws, b1, bn_g, bn_b, bn_m, bn_v, W2, b2, qw, W3, b3, out);
    } else {
        fused_qh_mfma<<<B / BM, 256, 0, stream>>>(
            x, W1, b1, bn_g, bn_b, bn_m, bn_v, W2, b2, qw, W3, b3, out);
    }
}

// Round 8
// 71.173 us; speedup vs baseline: 2.7640x; 1.7577x over previous
//
#include <hip/hip_runtime.h>
#include <math.h>

typedef __attribute__((ext_vector_type(8))) short bf16x8;
typedef __attribute__((ext_vector_type(4))) float f32x4;

constexpr int D   = 1280;  // input dim
constexpr int H   = 64;    // hidden
constexpr int BM  = 32;    // rows per block (N split across waves)
constexpr int KC  = 64;    // K chunk
constexpr int SW  = KC + 8;   // W-tile LDS row stride in bf16 (verified r2 layout)
constexpr int HSS = H + 1;

union FragU { bf16x8 v; unsigned int u[4]; };

// truncation split of two f32 into packed bf16 hi pair + bf16 lo pair
__device__ __forceinline__ unsigned int pack_split(float f0, float f1, unsigned int& lo) {
    unsigned int u0 = __float_as_uint(f0), u1 = __float_as_uint(f1);
    unsigned int h0 = u0 & 0xFFFF0000u,    h1 = u1 & 0xFFFF0000u;
    float l0 = f0 - __uint_as_float(h0);
    float l1 = f1 - __uint_as_float(h1);
    lo = (__float_as_uint(l1) & 0xFFFF0000u) | (__float_as_uint(l0) >> 16);
    return h1 | (u0 >> 16);
}

// ---------------- quantum gates: 4-qubit statevector, bit weight BW ----------
template<int BW>
__device__ __forceinline__ void ry_gate(float re[16], float im[16], float theta) {
    float sn, cs;
    sincosf(0.5f * theta, &sn, &cs);
#pragma unroll
    for (int s0 = 0; s0 < 16; ++s0) {
        if (s0 & BW) continue;
        const int s1 = s0 | BW;
        float r0 = re[s0], i0 = im[s0], r1 = re[s1], i1 = im[s1];
        re[s0] = cs * r0 - sn * r1;  im[s0] = cs * i0 - sn * i1;
        re[s1] = sn * r0 + cs * r1;  im[s1] = sn * i0 + cs * i1;
    }
}

template<int BW>
__device__ __forceinline__ void rz_gate(float re[16], float im[16], float theta) {
    float sn, cs;
    sincosf(0.5f * theta, &sn, &cs);
#pragma unroll
    for (int s0 = 0; s0 < 16; ++s0) {
        if (s0 & BW) continue;
        const int s1 = s0 | BW;
        float r0 = re[s0], i0 = im[s0], r1 = re[s1], i1 = im[s1];
        re[s0] = cs * r0 + sn * i0;  im[s0] = cs * i0 - sn * r0;
        re[s1] = cs * r1 - sn * i1;  im[s1] = cs * i1 + sn * r1;
    }
}

template<int BWC, int BWT>
__device__ __forceinline__ void cnot_gate(float re[16], float im[16]) {
#pragma unroll
    for (int s = 0; s < 16; ++s) {
        if (!(s & BWC)) continue;
        if (s & BWT) continue;
        const int t = s | BWT;
        float tr = re[s], ti = im[s];
        re[s] = re[t]; im[s] = im[t];
        re[t] = tr;    im[t] = ti;
    }
}

__device__ __forceinline__ void quantum_row(const float ang[4], const float* __restrict__ qw,
                                            const float* __restrict__ W3, const float* __restrict__ b3,
                                            float* __restrict__ o) {
    float re[16] = {}, im[16] = {};
    re[0] = 1.0f;
    ry_gate<8>(re, im, ang[0]);
    ry_gate<4>(re, im, ang[1]);
    ry_gate<2>(re, im, ang[2]);
    ry_gate<1>(re, im, ang[3]);
#pragma unroll
    for (int ll = 0; ll < 2; ++ll) {
        const float* qp = &qw[ll * 8];
        ry_gate<8>(re, im, qp[0]); rz_gate<8>(re, im, qp[1]);
        ry_gate<4>(re, im, qp[2]); rz_gate<4>(re, im, qp[3]);
        ry_gate<2>(re, im, qp[4]); rz_gate<2>(re, im, qp[5]);
        ry_gate<1>(re, im, qp[6]); rz_gate<1>(re, im, qp[7]);
        cnot_gate<8, 4>(re, im);
        cnot_gate<4, 2>(re, im);
        cnot_gate<2, 1>(re, im);
        cnot_gate<1, 8>(re, im);
    }
    float z[4] = {};
#pragma unroll
    for (int s = 0; s < 16; ++s) {
        float p = re[s] * re[s] + im[s] * im[s];
        z[0] += (s & 8) ? -p : p;
        z[1] += (s & 4) ? -p : p;
        z[2] += (s & 2) ? -p : p;
        z[3] += (s & 1) ? -p : p;
    }
#pragma unroll
    for (int c = 0; c < 10; ++c) {
        float v = b3[c];
#pragma unroll
        for (int i = 0; i < 4; ++i)
            v = fmaf(z[i], W3[c * 4 + i], v);
        o[c] = v;
    }
}

// ====== main kernel: verified r2 structure, BM=32 via wave-level N split ======
// wave w: wm = w&1 -> M stripe (rows wm*16..wm*16+15), wn = w>>1 -> N half
__global__ __launch_bounds__(256, 4)
void fused_qh_v8(const float* __restrict__ x,   const float* __restrict__ W1,
                 const float* __restrict__ b1,  const float* __restrict__ bn_g,
                 const float* __restrict__ bn_b,const float* __restrict__ bn_m,
                 const float* __restrict__ bn_v,const float* __restrict__ W2,
                 const float* __restrict__ b2,  const float* __restrict__ qw,
                 const float* __restrict__ W3,  const float* __restrict__ b3,
                 float* __restrict__ out)
{
    __shared__ short whi[H][SW];
    __shared__ short wlo[H][SW];
    __shared__ float hs[BM][HSS];
    __shared__ float w2s[4 * H];
    __shared__ float b1s[H], scl[H], shf[H];
    __shared__ float angs[BM][4];

    const int tid  = threadIdx.x;
    const int l    = tid & 63;
    const int w    = tid >> 6;      // 0..3
    const int wm   = w & 1;         // M stripe
    const int wn   = w >> 1;        // N half
    const int lr   = l & 15;
    const int lk   = l >> 4;
    const int row0 = blockIdx.x * BM;

    // prologue: small params to LDS
    w2s[tid] = W2[tid];
    if (tid < H) {
        float s = bn_g[tid] * rsqrtf(bn_v[tid] + 1e-5f);
        b1s[tid] = b1[tid];
        scl[tid] = s;
        shf[tid] = bn_b[tid] - bn_m[tid] * s;
    }

    const float4* xr4 = reinterpret_cast<const float4*>(x + (size_t)(row0 + wm * 16 + lr) * D);

    // W staging mapping (identical to verified r2): f4 = tid + it*256
    int sn[4], sk4[4];
#pragma unroll
    for (int it = 0; it < 4; ++it) {
        int f4 = tid + it * 256;
        sn[it]  = f4 >> 4;
        sk4[it] = (f4 & 15) * 4;
    }

    f32x4 acc[2] = {{0,0,0,0},{0,0,0,0}};
    float4 acur[4], anxt[4], wcur[4], wnxt[4];
#pragma unroll
    for (int it = 0; it < 4; ++it)
        wcur[it] = *reinterpret_cast<const float4*>(&W1[(size_t)sn[it] * D + sk4[it]]);
#pragma unroll
    for (int h = 0; h < 2; ++h)
#pragma unroll
        for (int p = 0; p < 2; ++p)
            acur[h * 2 + p] = xr4[h * 8 + lk * 2 + p];

    for (int k0 = 0; k0 < D; k0 += KC) {
        // ---- stage W tile (convert + LDS write), identical to r2 ----
#pragma unroll
        for (int it = 0; it < 4; ++it) {
            unsigned int lo01, lo23;
            unsigned int hi01 = pack_split(wcur[it].x, wcur[it].y, lo01);
            unsigned int hi23 = pack_split(wcur[it].z, wcur[it].w, lo23);
            uint2 hv; hv.x = hi01; hv.y = hi23;
            uint2 lv; lv.x = lo01; lv.y = lo23;
            *reinterpret_cast<uint2*>(&whi[sn[it]][sk4[it]]) = hv;
            *reinterpret_cast<uint2*>(&wlo[sn[it]][sk4[it]]) = lv;
        }
        // ---- prefetch next chunk into registers ----
        if (k0 + KC < D) {
            const int kn = k0 + KC;
#pragma unroll
            for (int it = 0; it < 4; ++it)
                wnxt[it] = *reinterpret_cast<const float4*>(&W1[(size_t)sn[it] * D + kn + sk4[it]]);
#pragma unroll
            for (int h = 0; h < 2; ++h)
#pragma unroll
                for (int p = 0; p < 2; ++p)
                    anxt[h * 2 + p] = xr4[kn / 4 + h * 8 + lk * 2 + p];
        }
        __syncthreads();

        // ---- A fragments (hi/lo) ----
        FragU ahi[2], alo[2];
#pragma unroll
        for (int h = 0; h < 2; ++h) {
            const float4 p0 = acur[h * 2 + 0];
            const float4 p1 = acur[h * 2 + 1];
            ahi[h].u[0] = pack_split(p0.x, p0.y, alo[h].u[0]);
            ahi[h].u[1] = pack_split(p0.z, p0.w, alo[h].u[1]);
            ahi[h].u[2] = pack_split(p1.x, p1.y, alo[h].u[2]);
            ahi[h].u[3] = pack_split(p1.z, p1.w, alo[h].u[3]);
        }

        // ---- MFMA: this wave's N half only ----
#pragma unroll
        for (int h = 0; h < 2; ++h)
#pragma unroll
            for (int g2 = 0; g2 < 2; ++g2) {
                const int g = wn * 2 + g2;
                const bf16x8 bh = *reinterpret_cast<const bf16x8*>(&whi[g * 16 + lr][h * 32 + lk * 8]);
                const bf16x8 bl = *reinterpret_cast<const bf16x8*>(&wlo[g * 16 + lr][h * 32 + lk * 8]);
                acc[g2] = __builtin_amdgcn_mfma_f32_16x16x32_bf16(ahi[h].v, bh, acc[g2], 0, 0, 0);
                acc[g2] = __builtin_amdgcn_mfma_f32_16x16x32_bf16(ahi[h].v, bl, acc[g2], 0, 0, 0);
                acc[g2] = __builtin_amdgcn_mfma_f32_16x16x32_bf16(alo[h].v, bh, acc[g2], 0, 0, 0);
            }
        __syncthreads();

#pragma unroll
        for (int it = 0; it < 4; ++it) { acur[it] = anxt[it]; wcur[it] = wnxt[it]; }
    }

    // epilogue 1: bias -> relu -> BN -> hs (C/D: col=g*16+lr, row=lk*4+reg)
#pragma unroll
    for (int g2 = 0; g2 < 2; ++g2) {
        const int cc = (wn * 2 + g2) * 16 + lr;
        const float b1c = b1s[cc], s = scl[cc], sh = shf[cc];
#pragma unroll
        for (int r = 0; r < 4; ++r) {
            float v = acc[g2][r] + b1c;
            v = fmaxf(v, 0.0f) * s + sh;
            hs[wm * 16 + lk * 4 + r][cc] = v;
        }
    }
    __syncthreads();

    // epilogue 2a: GEMM2 + double tanh, 4 threads per row (128 = 32 rows * 4)
    if (tid < 4 * BM) {
        const int row = tid >> 2, qi = tid & 3;
        float a2v = b2[qi];
#pragma unroll
        for (int k = 0; k < H; ++k)
            a2v = fmaf(hs[row][k], w2s[qi * H + k], a2v);
        float xq = tanhf(a2v);
        angs[row][qi] = tanhf(xq) * 3.14159265358979323846f;
    }
    __syncthreads();

    // epilogue 2b: quantum circuit + GEMM3, one thread per row
    if (tid < BM) {
        float ang[4] = { angs[tid][0], angs[tid][1], angs[tid][2], angs[tid][3] };
        quantum_row(ang, qw, W3, b3, &out[(size_t)(row0 + tid) * 10]);
    }
}

extern "C" void kernel_launch(void* const* d_in, const int* in_sizes, int n_in,
                              void* d_out, int out_size, void* d_ws, size_t ws_size,
                              hipStream_t stream) {
    const float* x    = (const float*)d_in[0];
    const float* W1   = (const float*)d_in[1];
    const float* b1   = (const float*)d_in[2];
    const float* bn_g = (const float*)d_in[3];
    const float* bn_b = (const float*)d_in[4];
    const float* bn_m = (const float*)d_in[5];
    const float* bn_v = (const float*)d_in[6];
    const float* W2   = (const float*)d_in[7];
    const float* b2   = (const float*)d_in[8];
    const float* qw   = (const float*)d_in[9];
    const float* W3   = (const float*)d_in[10];
    const float* b3   = (const float*)d_in[11];
    float* out = (float*)d_out;

    const int B = in_sizes[0] / D;   // 32768
    const int grid = B / BM;         // 1024 -> 4 blocks/CU

    fused_qh_v8<<<grid, 256, 0, stream>>>(
        x, W1, b1, bn_g, bn_b, bn_m, bn_v, W2, b2, qw, W3, b3, out);
}

// Round 9
// 43.480 us; speedup vs baseline: 4.5245x; 1.6369x over previous
//
#include <hip/hip_runtime.h>
#include <math.h>

typedef __attribute__((ext_vector_type(8))) short bf16x8;
typedef __attribute__((ext_vector_type(4))) float f32x4;

constexpr int D   = 1280;  // input dim
constexpr int H   = 64;    // hidden
constexpr int BM  = 128;   // rows per block
constexpr int NT  = 512;   // threads per block (8 waves)
constexpr int KC  = 64;    // K chunk
constexpr int SW  = KC + 8;   // W-tile LDS row stride in bf16 (verified r2 layout)
constexpr int HSS = H + 1;

union FragU { bf16x8 v; unsigned int u[4]; };

// truncation split of two f32 into packed bf16 hi pair + bf16 lo pair
__device__ __forceinline__ unsigned int pack_split(float f0, float f1, unsigned int& lo) {
    unsigned int u0 = __float_as_uint(f0), u1 = __float_as_uint(f1);
    unsigned int h0 = u0 & 0xFFFF0000u,    h1 = u1 & 0xFFFF0000u;
    float l0 = f0 - __uint_as_float(h0);
    float l1 = f1 - __uint_as_float(h1);
    lo = (__float_as_uint(l1) & 0xFFFF0000u) | (__float_as_uint(l0) >> 16);
    return h1 | (u0 >> 16);
}

// ---------------- quantum gates: 4-qubit statevector, bit weight BW ----------
template<int BW>
__device__ __forceinline__ void ry_gate(float re[16], float im[16], float theta) {
    float sn, cs;
    sincosf(0.5f * theta, &sn, &cs);
#pragma unroll
    for (int s0 = 0; s0 < 16; ++s0) {
        if (s0 & BW) continue;
        const int s1 = s0 | BW;
        float r0 = re[s0], i0 = im[s0], r1 = re[s1], i1 = im[s1];
        re[s0] = cs * r0 - sn * r1;  im[s0] = cs * i0 - sn * i1;
        re[s1] = sn * r0 + cs * r1;  im[s1] = sn * i0 + cs * i1;
    }
}

template<int BW>
__device__ __forceinline__ void rz_gate(float re[16], float im[16], float theta) {
    float sn, cs;
    sincosf(0.5f * theta, &sn, &cs);
#pragma unroll
    for (int s0 = 0; s0 < 16; ++s0) {
        if (s0 & BW) continue;
        const int s1 = s0 | BW;
        float r0 = re[s0], i0 = im[s0], r1 = re[s1], i1 = im[s1];
        re[s0] = cs * r0 + sn * i0;  im[s0] = cs * i0 - sn * r0;
        re[s1] = cs * r1 - sn * i1;  im[s1] = cs * i1 + sn * r1;
    }
}

template<int BWC, int BWT>
__device__ __forceinline__ void cnot_gate(float re[16], float im[16]) {
#pragma unroll
    for (int s = 0; s < 16; ++s) {
        if (!(s & BWC)) continue;
        if (s & BWT) continue;
        const int t = s | BWT;
        float tr = re[s], ti = im[s];
        re[s] = re[t]; im[s] = im[t];
        re[t] = tr;    im[t] = ti;
    }
}

__device__ __forceinline__ void quantum_row(const float ang[4], const float* __restrict__ qw,
                                            const float* __restrict__ W3, const float* __restrict__ b3,
                                            float* __restrict__ o) {
    float re[16] = {}, im[16] = {};
    re[0] = 1.0f;
    ry_gate<8>(re, im, ang[0]);
    ry_gate<4>(re, im, ang[1]);
    ry_gate<2>(re, im, ang[2]);
    ry_gate<1>(re, im, ang[3]);
#pragma unroll
    for (int ll = 0; ll < 2; ++ll) {
        const float* qp = &qw[ll * 8];
        ry_gate<8>(re, im, qp[0]); rz_gate<8>(re, im, qp[1]);
        ry_gate<4>(re, im, qp[2]); rz_gate<4>(re, im, qp[3]);
        ry_gate<2>(re, im, qp[4]); rz_gate<2>(re, im, qp[5]);
        ry_gate<1>(re, im, qp[6]); rz_gate<1>(re, im, qp[7]);
        cnot_gate<8, 4>(re, im);
        cnot_gate<4, 2>(re, im);
        cnot_gate<2, 1>(re, im);
        cnot_gate<1, 8>(re, im);
    }
    float z[4] = {};
#pragma unroll
    for (int s = 0; s < 16; ++s) {
        float p = re[s] * re[s] + im[s] * im[s];
        z[0] += (s & 8) ? -p : p;
        z[1] += (s & 4) ? -p : p;
        z[2] += (s & 2) ? -p : p;
        z[3] += (s & 1) ? -p : p;
    }
#pragma unroll
    for (int c = 0; c < 10; ++c) {
        float v = b3[c];
#pragma unroll
        for (int i = 0; i < 4; ++i)
            v = fmaf(z[i], W3[c * 4 + i], v);
        o[c] = v;
    }
}

// ====== main kernel: verified r2 template at BM=128 / 512 threads ============
__global__ __launch_bounds__(512, 2)
void fused_qh_v9(const float* __restrict__ x,   const float* __restrict__ W1,
                 const float* __restrict__ b1,  const float* __restrict__ bn_g,
                 const float* __restrict__ bn_b,const float* __restrict__ bn_m,
                 const float* __restrict__ bn_v,const float* __restrict__ W2,
                 const float* __restrict__ b2,  const float* __restrict__ qw,
                 const float* __restrict__ W3,  const float* __restrict__ b3,
                 float* __restrict__ out)
{
    __shared__ short whi[H][SW];
    __shared__ short wlo[H][SW];
    __shared__ float hs[BM][HSS];
    __shared__ float w2s[4 * H];
    __shared__ float b1s[H], scl[H], shf[H];
    __shared__ float angs[BM][4];

    const int tid  = threadIdx.x;   // 0..511
    const int l    = tid & 63;
    const int w    = tid >> 6;      // wave 0..7 -> 16-row M stripe
    const int lr   = l & 15;
    const int lk   = l >> 4;
    const int row0 = blockIdx.x * BM;

    // prologue: small params to LDS
    if (tid < 256) w2s[tid] = W2[tid];
    if (tid < H) {
        float s = bn_g[tid] * rsqrtf(bn_v[tid] + 1e-5f);
        b1s[tid] = b1[tid];
        scl[tid] = s;
        shf[tid] = bn_b[tid] - bn_m[tid] * s;
    }

    const float4* xr4 = reinterpret_cast<const float4*>(x + (size_t)(row0 + w * 16 + lr) * D);

    // W staging mapping (r2 formula, 512 threads): f4 = tid + it*512, it=0..1
    int sn[2], sk4[2];
#pragma unroll
    for (int it = 0; it < 2; ++it) {
        int f4 = tid + it * 512;
        sn[it]  = f4 >> 4;          // 0..63
        sk4[it] = (f4 & 15) * 4;    // 0..60
    }

    f32x4 acc[4] = {{0,0,0,0},{0,0,0,0},{0,0,0,0},{0,0,0,0}};
    float4 acur[4], anxt[4], wcur[2], wnxt[2];
#pragma unroll
    for (int it = 0; it < 2; ++it)
        wcur[it] = *reinterpret_cast<const float4*>(&W1[(size_t)sn[it] * D + sk4[it]]);
#pragma unroll
    for (int h = 0; h < 2; ++h)
#pragma unroll
        for (int p = 0; p < 2; ++p)
            acur[h * 2 + p] = xr4[h * 8 + lk * 2 + p];

    for (int k0 = 0; k0 < D; k0 += KC) {
        // ---- stage W tile (convert + LDS write), r2-identical pattern ----
#pragma unroll
        for (int it = 0; it < 2; ++it) {
            unsigned int lo01, lo23;
            unsigned int hi01 = pack_split(wcur[it].x, wcur[it].y, lo01);
            unsigned int hi23 = pack_split(wcur[it].z, wcur[it].w, lo23);
            uint2 hv; hv.x = hi01; hv.y = hi23;
            uint2 lv; lv.x = lo01; lv.y = lo23;
            *reinterpret_cast<uint2*>(&whi[sn[it]][sk4[it]]) = hv;
            *reinterpret_cast<uint2*>(&wlo[sn[it]][sk4[it]]) = lv;
        }
        // ---- prefetch next chunk into registers ----
        if (k0 + KC < D) {
            const int kn = k0 + KC;
#pragma unroll
            for (int it = 0; it < 2; ++it)
                wnxt[it] = *reinterpret_cast<const float4*>(&W1[(size_t)sn[it] * D + kn + sk4[it]]);
#pragma unroll
            for (int h = 0; h < 2; ++h)
#pragma unroll
                for (int p = 0; p < 2; ++p)
                    anxt[h * 2 + p] = xr4[kn / 4 + h * 8 + lk * 2 + p];
        }
        __syncthreads();

        // ---- A fragments (hi/lo) ----
        FragU ahi[2], alo[2];
#pragma unroll
        for (int h = 0; h < 2; ++h) {
            const float4 p0 = acur[h * 2 + 0];
            const float4 p1 = acur[h * 2 + 1];
            ahi[h].u[0] = pack_split(p0.x, p0.y, alo[h].u[0]);
            ahi[h].u[1] = pack_split(p0.z, p0.w, alo[h].u[1]);
            ahi[h].u[2] = pack_split(p1.x, p1.y, alo[h].u[2]);
            ahi[h].u[3] = pack_split(p1.z, p1.w, alo[h].u[3]);
        }

        // ---- MFMA: full 64-col tile per wave (r2-identical) ----
#pragma unroll
        for (int h = 0; h < 2; ++h)
#pragma unroll
            for (int g = 0; g < 4; ++g) {
                const bf16x8 bh = *reinterpret_cast<const bf16x8*>(&whi[g * 16 + lr][h * 32 + lk * 8]);
                const bf16x8 bl = *reinterpret_cast<const bf16x8*>(&wlo[g * 16 + lr][h * 32 + lk * 8]);
                acc[g] = __builtin_amdgcn_mfma_f32_16x16x32_bf16(ahi[h].v, bh, acc[g], 0, 0, 0);
                acc[g] = __builtin_amdgcn_mfma_f32_16x16x32_bf16(ahi[h].v, bl, acc[g], 0, 0, 0);
                acc[g] = __builtin_amdgcn_mfma_f32_16x16x32_bf16(alo[h].v, bh, acc[g], 0, 0, 0);
            }
        __syncthreads();

#pragma unroll
        for (int it = 0; it < 2; ++it) wcur[it] = wnxt[it];
#pragma unroll
        for (int i = 0; i < 4; ++i) acur[i] = anxt[i];
    }

    // epilogue 1: bias -> relu -> BN -> hs (C/D: col=g*16+lr, row=lk*4+reg)
#pragma unroll
    for (int g = 0; g < 4; ++g) {
        const int cc = g * 16 + lr;
        const float b1c = b1s[cc], s = scl[cc], sh = shf[cc];
#pragma unroll
        for (int r = 0; r < 4; ++r) {
            float v = acc[g][r] + b1c;
            v = fmaxf(v, 0.0f) * s + sh;
            hs[w * 16 + lk * 4 + r][cc] = v;
        }
    }
    __syncthreads();

    // epilogue 2a: GEMM2 + double tanh, 4 threads per row (512 = 128 rows * 4)
    {
        const int row = tid >> 2, qi = tid & 3;
        float a2v = b2[qi];
#pragma unroll
        for (int k = 0; k < H; ++k)
            a2v = fmaf(hs[row][k], w2s[qi * H + k], a2v);
        float xq = tanhf(a2v);
        angs[row][qi] = tanhf(xq) * 3.14159265358979323846f;
    }
    __syncthreads();

    // epilogue 2b: quantum circuit + GEMM3, one thread per row
    if (tid < BM) {
        float ang[4] = { angs[tid][0], angs[tid][1], angs[tid][2], angs[tid][3] };
        quantum_row(ang, qw, W3, b3, &out[(size_t)(row0 + tid) * 10]);
    }
}

extern "C" void kernel_launch(void* const* d_in, const int* in_sizes, int n_in,
                              void* d_out, int out_size, void* d_ws, size_t ws_size,
                              hipStream_t stream) {
    const float* x    = (const float*)d_in[0];
    const float* W1   = (const float*)d_in[1];
    const float* b1   = (const float*)d_in[2];
    const float* bn_g = (const float*)d_in[3];
    const float* bn_b = (const float*)d_in[4];
    const float* bn_m = (const float*)d_in[5];
    const float* bn_v = (const float*)d_in[6];
    const float* W2   = (const float*)d_in[7];
    const float* b2   = (const float*)d_in[8];
    const float* qw   = (const float*)d_in[9];
    const float* W3   = (const float*)d_in[10];
    const float* b3   = (const float*)d_in[11];
    float* out = (float*)d_out;

    const int B = in_sizes[0] / D;   // 32768
    const int grid = B / BM;         // 256 -> 1 block/CU

    fused_qh_v9<<<grid, NT, 0, stream>>>(
        x, W1, b1, bn_g, bn_b, bn_m, bn_v, W2, b2, qw, W3, b3, out);
}